// Round 2
// baseline (205.893 us; speedup 1.0000x reference)
//
#include <hip/hip_runtime.h>
#include <math.h>

// Literal gate-by-gate VQC simulator. One wave64 per batch element, state in LDS.
// Amplitude index a (8 bits): wire w <-> bit (7-w) of a (row-major reshape of the
// reference's (B, 2,2,...,2) tensor).
//
// 1q gate on bit p: 128 disjoint pairs (a0, a0|1<<p); lane handles pair i=lane, lane+64.
// 2q gate (control bit pc, target bit pt): 64 disjoint pairs among control=1 amps;
// lane handles one pair. __syncthreads() between gates (uniform control flow).

__global__ __launch_bounds__(256) void vqc_lit_kernel(
    const float* __restrict__ x,
    const float* __restrict__ gt,
    const float* __restrict__ W1,
    const float* __restrict__ b1,
    const float* __restrict__ W2,
    const float* __restrict__ b2,
    float* __restrict__ out, int Btot)
{
    __shared__ float S_RE[4][256];
    __shared__ float S_IM[4][256];

    const int lane = threadIdx.x & 63;
    const int wv   = threadIdx.x >> 6;
    const int b    = blockIdx.x * 4 + wv;
    const bool valid = (b < Btot);
    const int bb = valid ? b : 0;

    float* re = S_RE[wv];
    float* im = S_IM[wv];

    const float theta = x[2 * bb + 0];
    const float phi   = x[2 * bb + 1];
    const float ct = cosf(0.5f * theta);
    const float st = sinf(0.5f * theta);
    const float zc = cosf(0.5f * phi);
    const float zs = sinf(0.5f * phi);
    // RZ per wire: bit=0 -> multiply by (zc, -zs); bit=1 -> (zc, +zs)

    // init |0...0>
    #pragma unroll
    for (int k = 0; k < 4; ++k) { re[lane * 4 + k] = 0.f; im[lane * 4 + k] = 0.f; }
    if (lane == 0) re[0] = 1.f;
    __syncthreads();

    for (int cyc = 0; cyc < 4; ++cyc) {
        // ---- RX on wires 0..7 ----
        for (int w = 0; w < 8; ++w) {
            const int p = 7 - w;
            #pragma unroll
            for (int k = 0; k < 2; ++k) {
                const int i  = lane + 64 * k;
                const int a0 = ((i >> p) << (p + 1)) | (i & ((1 << p) - 1));
                const int a1 = a0 | (1 << p);
                const float r0 = re[a0], i0 = im[a0];
                const float r1 = re[a1], i1 = im[a1];
                // RX: new0 = c*o0 + (-i s)*o1 ; new1 = (-i s)*o0 + c*o1
                re[a0] = ct * r0 + st * i1;  im[a0] = ct * i0 - st * r1;
                re[a1] = ct * r1 + st * i0;  im[a1] = ct * i1 - st * r0;
            }
            __syncthreads();
        }
        // ---- RZ on wires 0..7 (lane-local: each lane owns amps 4*lane..4*lane+3) ----
        #pragma unroll
        for (int k = 0; k < 4; ++k) {
            const int a = lane * 4 + k;
            float r = re[a], ii = im[a];
            #pragma unroll
            for (int w = 0; w < 8; ++w) {
                const int p = 7 - w;
                const float s = ((a >> p) & 1) ? zs : -zs;
                const float nr = r * zc - ii * s;
                const float ni = r * s + ii * zc;
                r = nr; ii = ni;
            }
            re[a] = r; im[a] = ii;
        }
        __syncthreads();
        // ---- CNOT ring w -> (w+1)%8 ----
        for (int w = 0; w < 8; ++w) {
            const int pc = 7 - w;
            const int pt = 7 - ((w + 1) & 7);
            const int lo = pc < pt ? pc : pt;
            const int hi = pc < pt ? pt : pc;
            const int i    = lane;
            const int t0   = i & ((1 << lo) - 1);
            const int rest = i >> lo;
            const int mid  = rest & ((1 << (hi - lo - 1)) - 1);
            const int top  = rest >> (hi - lo - 1);
            const int base = t0 | (mid << (lo + 1)) | (top << (hi + 1));
            const int a0 = base | (1 << pc);     // control=1, target=0
            const int a1 = a0 | (1 << pt);       // control=1, target=1
            const float r0 = re[a0], i0 = im[a0];
            const float r1 = re[a1], i1 = im[a1];
            re[a0] = r1; im[a0] = i1;
            re[a1] = r0; im[a1] = i0;
            __syncthreads();
        }
    }

    // ---- 10 CRX gates: control i%8, target (i+1)%8 ----
    for (int g = 0; g < 10; ++g) {
        const float c = cosf(0.5f * gt[g]);
        const float s = sinf(0.5f * gt[g]);
        const int cw = g & 7;
        const int tw = (g + 1) & 7;
        const int pc = 7 - cw;
        const int pt = 7 - tw;
        const int lo = pc < pt ? pc : pt;
        const int hi = pc < pt ? pt : pc;
        const int i    = lane;
        const int t0   = i & ((1 << lo) - 1);
        const int rest = i >> lo;
        const int mid  = rest & ((1 << (hi - lo - 1)) - 1);
        const int top  = rest >> (hi - lo - 1);
        const int base = t0 | (mid << (lo + 1)) | (top << (hi + 1));
        const int a0 = base | (1 << pc);
        const int a1 = a0 | (1 << pt);
        const float r0 = re[a0], i0 = im[a0];
        const float r1 = re[a1], i1 = im[a1];
        re[a0] = c * r0 + s * i1;  im[a0] = c * i0 - s * r1;
        re[a1] = c * r1 + s * i0;  im[a1] = c * i1 - s * r0;
        __syncthreads();
    }

    // ---- expectation values <Z_3> (bit 4), <Z_7> (bit 0) ----
    float e3 = 0.f, e7 = 0.f;
    #pragma unroll
    for (int k = 0; k < 4; ++k) {
        const int a = lane * 4 + k;
        const float p = re[a] * re[a] + im[a] * im[a];
        e3 += ((a >> 4) & 1) ? -p : p;
        e7 += (a & 1) ? -p : p;
    }
    #pragma unroll
    for (int m = 1; m < 64; m <<= 1) {
        e3 += __shfl_xor(e3, m, 64);
        e7 += __shfl_xor(e7, m, 64);
    }

    // ---- MLP head ----
    if (valid && lane == 0) {
        float acc = b2[0];
        #pragma unroll
        for (int j = 0; j < 10; ++j) {
            float h = tanhf(W1[2 * j] * e3 + W1[2 * j + 1] * e7 + b1[j]);
            acc += W2[j] * h;
        }
        out[b] = 1.0f / (1.0f + expf(-acc));
    }
}

extern "C" void kernel_launch(void* const* d_in, const int* in_sizes, int n_in,
                              void* d_out, int out_size, void* d_ws, size_t ws_size,
                              hipStream_t stream) {
    const float* x  = (const float*)d_in[0];
    const float* gt = (const float*)d_in[1];
    const float* W1 = (const float*)d_in[2];
    const float* b1 = (const float*)d_in[3];
    const float* W2 = (const float*)d_in[4];
    const float* b2 = (const float*)d_in[5];
    float* out = (float*)d_out;

    const int Btot = in_sizes[0] / 2;   // x is (B, 2)
    const int blocks = (Btot + 3) / 4;  // 4 waves (batch elements) per 256-thread block

    vqc_lit_kernel<<<blocks, 256, 0, stream>>>(x, gt, W1, b1, W2, b2, out, Btot);
}

// Round 5
// 183.758 us; speedup vs baseline: 1.1205x; 1.1205x over previous
//
#include <hip/hip_runtime.h>
#include <math.h>

// Wave-private LDS VQC simulator — bisection round: round-1-verified gate code
// (including PER-WIRE RZ, verbatim) with only two mechanical changes:
//   1. no __syncthreads (state is wave-private; WFENCE = compiler fence only)
//   2. float2-interleaved LDS layout (ds b64 instead of 2x b32)
// Round 3 (same changes + fused RZ) failed at 0.03125; if this passes, the
// RZ fusion is proven to be the bug.
// Amplitude index a (8 bits): wire w <-> bit (7-w).

#define WFENCE() do { asm volatile("" ::: "memory"); __builtin_amdgcn_wave_barrier(); } while (0)

__global__ __launch_bounds__(256) void vqc_wave_kernel(
    const float* __restrict__ x,
    const float* __restrict__ gt,
    const float* __restrict__ W1,
    const float* __restrict__ b1,
    const float* __restrict__ W2,
    const float* __restrict__ b2,
    float* __restrict__ out, int Btot)
{
    __shared__ float2 AMP[4][256];

    const int lane = threadIdx.x & 63;
    const int wv   = threadIdx.x >> 6;
    const int b    = blockIdx.x * 4 + wv;
    const bool valid = (b < Btot);
    const int bb = valid ? b : 0;

    float2* amp = AMP[wv];

    const float theta = x[2 * bb + 0];
    const float phi   = x[2 * bb + 1];
    const float ct = cosf(0.5f * theta);
    const float sn = sinf(0.5f * theta);
    const float zc = cosf(0.5f * phi);
    const float zs = sinf(0.5f * phi);
    // RZ per wire (round-1 verbatim): bit=0 -> multiply by (zc, -zs); bit=1 -> (zc, +zs)

    // init |0...0>
    #pragma unroll
    for (int k = 0; k < 4; ++k) amp[4 * lane + k] = make_float2(0.f, 0.f);
    if (lane == 0) amp[0] = make_float2(1.f, 0.f);
    WFENCE();

    #pragma unroll 1
    for (int cyc = 0; cyc < 4; ++cyc) {
        // ---- RX on wires 0..7 (bit p = 7-w); 128 pairs, 2 per lane ----
        #pragma unroll
        for (int w = 0; w < 8; ++w) {
            const int p = 7 - w;
            #pragma unroll
            for (int k = 0; k < 2; ++k) {
                const int i  = lane + 64 * k;
                const int a0 = ((i >> p) << (p + 1)) | (i & ((1 << p) - 1));
                const int a1 = a0 | (1 << p);
                const float2 o0 = amp[a0];
                const float2 o1 = amp[a1];
                amp[a0] = make_float2(ct * o0.x + sn * o1.y, ct * o0.y - sn * o1.x);
                amp[a1] = make_float2(ct * o1.x + sn * o0.y, ct * o1.y - sn * o0.x);
            }
            WFENCE();
        }
        // ---- RZ on wires 0..7, per-wire, lane-local (round-1 verbatim) ----
        #pragma unroll
        for (int k = 0; k < 4; ++k) {
            const int a = 4 * lane + k;
            float2 o = amp[a];
            #pragma unroll
            for (int w = 0; w < 8; ++w) {
                const int p = 7 - w;
                const float s = ((a >> p) & 1) ? zs : -zs;
                const float nr = o.x * zc - o.y * s;
                const float ni = o.x * s + o.y * zc;
                o.x = nr; o.y = ni;
            }
            amp[a] = o;
        }
        WFENCE();
        // ---- CNOT ring w -> (w+1)%8; 64 control=1 pairs, 1 per lane ----
        #pragma unroll
        for (int w = 0; w < 8; ++w) {
            const int pc = 7 - w;
            const int pt = 7 - ((w + 1) & 7);
            const int lo = pc < pt ? pc : pt;
            const int hi = pc < pt ? pt : pc;
            const int t0   = lane & ((1 << lo) - 1);
            const int rest = lane >> lo;
            const int mid  = rest & ((1 << (hi - lo - 1)) - 1);
            const int top  = rest >> (hi - lo - 1);
            const int base = t0 | (mid << (lo + 1)) | (top << (hi + 1));
            const int a0 = base | (1 << pc);   // control=1, target=0
            const int a1 = a0 | (1 << pt);     // control=1, target=1
            const float2 o0 = amp[a0];
            const float2 o1 = amp[a1];
            amp[a0] = o1;
            amp[a1] = o0;
            WFENCE();
        }
    }

    // ---- 10 CRX gates: control g%8, target (g+1)%8 ----
    #pragma unroll
    for (int g = 0; g < 10; ++g) {
        const float c = cosf(0.5f * gt[g]);
        const float s = sinf(0.5f * gt[g]);
        const int pc = 7 - (g & 7);
        const int pt = 7 - ((g + 1) & 7);
        const int lo = pc < pt ? pc : pt;
        const int hi = pc < pt ? pt : pc;
        const int t0   = lane & ((1 << lo) - 1);
        const int rest = lane >> lo;
        const int mid  = rest & ((1 << (hi - lo - 1)) - 1);
        const int top  = rest >> (hi - lo - 1);
        const int base = t0 | (mid << (lo + 1)) | (top << (hi + 1));
        const int a0 = base | (1 << pc);
        const int a1 = a0 | (1 << pt);
        const float2 o0 = amp[a0];
        const float2 o1 = amp[a1];
        amp[a0] = make_float2(c * o0.x + s * o1.y, c * o0.y - s * o1.x);
        amp[a1] = make_float2(c * o1.x + s * o0.y, c * o1.y - s * o0.x);
        WFENCE();
    }

    // ---- expectation values <Z_3> (bit 4), <Z_7> (bit 0) ----
    float e3 = 0.f, e7 = 0.f;
    #pragma unroll
    for (int k = 0; k < 4; ++k) {
        const int a = 4 * lane + k;
        const float2 o = amp[a];
        const float p = o.x * o.x + o.y * o.y;
        e3 += ((a >> 4) & 1) ? -p : p;
        e7 += (a & 1) ? -p : p;
    }
    #pragma unroll
    for (int m = 1; m < 64; m <<= 1) {
        e3 += __shfl_xor(e3, m, 64);
        e7 += __shfl_xor(e7, m, 64);
    }

    // ---- MLP head (serial on lane 0; round-1 verbatim) ----
    if (valid && lane == 0) {
        float acc = b2[0];
        #pragma unroll
        for (int j = 0; j < 10; ++j) {
            float h = tanhf(W1[2 * j] * e3 + W1[2 * j + 1] * e7 + b1[j]);
            acc += W2[j] * h;
        }
        out[b] = 1.0f / (1.0f + expf(-acc));
    }
}

extern "C" void kernel_launch(void* const* d_in, const int* in_sizes, int n_in,
                              void* d_out, int out_size, void* d_ws, size_t ws_size,
                              hipStream_t stream) {
    const float* x  = (const float*)d_in[0];
    const float* gt = (const float*)d_in[1];
    const float* W1 = (const float*)d_in[2];
    const float* b1 = (const float*)d_in[3];
    const float* W2 = (const float*)d_in[4];
    const float* b2 = (const float*)d_in[5];
    float* out = (float*)d_out;

    const int Btot = in_sizes[0] / 2;   // x is (B, 2)
    const int blocks = (Btot + 3) / 4;  // 4 waves (batch elements) per 256-thread block

    vqc_wave_kernel<<<blocks, 256, 0, stream>>>(x, gt, W1, b1, W2, b2, out, Btot);
}

// Round 6
// 158.383 us; speedup vs baseline: 1.3000x; 1.1602x over previous
//
#include <hip/hip_runtime.h>
#include <math.h>

// Register-resident VQC simulator. One wave64 per batch element.
// Amplitude index a = (lane<<2) | r  (r = slot 0..3). Wire w <-> bit P = 7-w.
// Bits 7..2 of a = lane bits 5..0; bits 1..0 = slot bits.
// RZ: per-wire small-angle loop (verbatim from round-4 kernel, verified absmax 0.0).
// NOTE: fused-RZ via cosf/sinf of phi*(popc-4) (args up to 8*pi) is BROKEN on this
// toolchain (bisected rounds 3 vs 4) — never take trig of args outside [-pi, pi].

__device__ __forceinline__ float shflx(float v, int m) { return __shfl_xor(v, m, 64); }

// ---- generic 1q RX on amplitude bit P ----
template<int P>
__device__ __forceinline__ void rx_bit(float (&ar)[4], float (&ai)[4],
                                       float ct, float st) {
    if constexpr (P >= 2) {
        constexpr int m = 1 << (P - 2);
        #pragma unroll
        for (int r = 0; r < 4; ++r) {
            float pr = shflx(ar[r], m), pi = shflx(ai[r], m);
            float nr = ct * ar[r] + st * pi;
            float ni = ct * ai[r] - st * pr;
            ar[r] = nr; ai[r] = ni;
        }
    } else {
        float nr[4], ni[4];
        #pragma unroll
        for (int r = 0; r < 4; ++r) {
            const int rp = r ^ (1 << P);
            nr[r] = ct * ar[r] + st * ai[rp];
            ni[r] = ct * ai[r] - st * ar[rp];
        }
        #pragma unroll
        for (int r = 0; r < 4; ++r) { ar[r] = nr[r]; ai[r] = ni[r]; }
    }
}

// ---- generic CNOT: control bit PC, target bit PT ----
template<int PC, int PT>
__device__ __forceinline__ void cnot_bits(int lane, float (&ar)[4], float (&ai)[4]) {
    if constexpr (PT >= 2) {
        constexpr int m = 1 << (PT - 2);
        #pragma unroll
        for (int r = 0; r < 4; ++r) {
            bool ctrl;
            if constexpr (PC >= 2) ctrl = (lane >> (PC - 2)) & 1;
            else                   ctrl = (r >> PC) & 1;
            float pr = shflx(ar[r], m), pi = shflx(ai[r], m);
            ar[r] = ctrl ? pr : ar[r];
            ai[r] = ctrl ? pi : ai[r];
        }
    } else {
        float nr[4], ni[4];
        #pragma unroll
        for (int r = 0; r < 4; ++r) {
            const int rp = r ^ (1 << PT);
            bool ctrl;
            if constexpr (PC >= 2) ctrl = (lane >> (PC - 2)) & 1;
            else                   ctrl = (r >> PC) & 1;
            nr[r] = ctrl ? ar[rp] : ar[r];
            ni[r] = ctrl ? ai[rp] : ai[r];
        }
        #pragma unroll
        for (int r = 0; r < 4; ++r) { ar[r] = nr[r]; ai[r] = ni[r]; }
    }
}

// ---- generic CRX: control bit PC, target bit PT ----
template<int PC, int PT>
__device__ __forceinline__ void crx_bits(int lane, float c, float s,
                                         float (&ar)[4], float (&ai)[4]) {
    if constexpr (PT >= 2) {
        constexpr int m = 1 << (PT - 2);
        #pragma unroll
        for (int r = 0; r < 4; ++r) {
            bool ctrl;
            if constexpr (PC >= 2) ctrl = (lane >> (PC - 2)) & 1;
            else                   ctrl = (r >> PC) & 1;
            float pr = shflx(ar[r], m), pi = shflx(ai[r], m);
            float nr = c * ar[r] + s * pi;
            float ni = c * ai[r] - s * pr;
            ar[r] = ctrl ? nr : ar[r];
            ai[r] = ctrl ? ni : ai[r];
        }
    } else {
        float nr[4], ni[4];
        #pragma unroll
        for (int r = 0; r < 4; ++r) {
            const int rp = r ^ (1 << PT);
            bool ctrl;
            if constexpr (PC >= 2) ctrl = (lane >> (PC - 2)) & 1;
            else                   ctrl = (r >> PC) & 1;
            float vr = c * ar[r] + s * ai[rp];
            float vi = c * ai[r] - s * ar[rp];
            nr[r] = ctrl ? vr : ar[r];
            ni[r] = ctrl ? vi : ai[r];
        }
        #pragma unroll
        for (int r = 0; r < 4; ++r) { ar[r] = nr[r]; ai[r] = ni[r]; }
    }
}

__global__ __launch_bounds__(256) void vqc_reg_kernel(
    const float* __restrict__ x,
    const float* __restrict__ gt,
    const float* __restrict__ W1,
    const float* __restrict__ b1,
    const float* __restrict__ W2,
    const float* __restrict__ b2,
    float* __restrict__ out, int Btot)
{
    const int lane = threadIdx.x & 63;
    const int b = blockIdx.x * 4 + (threadIdx.x >> 6);
    const bool valid = (b < Btot);
    const int bb = valid ? b : 0;

    const float theta = x[2 * bb + 0];
    const float phi   = x[2 * bb + 1];

    const float ct = cosf(0.5f * theta);
    const float st = sinf(0.5f * theta);
    const float zc = cosf(0.5f * phi);
    const float zs = sinf(0.5f * phi);
    // RZ per wire: bit=0 -> multiply by (zc, -zs); bit=1 -> (zc, +zs)

    float ar[4], ai[4];
    #pragma unroll
    for (int r = 0; r < 4; ++r) { ar[r] = 0.f; ai[r] = 0.f; }
    if (lane == 0) ar[0] = 1.f;

    #pragma unroll 1
    for (int cyc = 0; cyc < 4; ++cyc) {
        // RX on wires 0..7 (commuting; any order)
        rx_bit<7>(ar, ai, ct, st);
        rx_bit<6>(ar, ai, ct, st);
        rx_bit<5>(ar, ai, ct, st);
        rx_bit<4>(ar, ai, ct, st);
        rx_bit<3>(ar, ai, ct, st);
        rx_bit<2>(ar, ai, ct, st);
        rx_bit<1>(ar, ai, ct, st);
        rx_bit<0>(ar, ai, ct, st);
        // RZ on wires 0..7, per-wire, lane-local (round-4 verbatim arithmetic)
        #pragma unroll
        for (int r = 0; r < 4; ++r) {
            const int a = (lane << 2) | r;
            float rx_ = ar[r], ix_ = ai[r];
            #pragma unroll
            for (int w = 0; w < 8; ++w) {
                const int p = 7 - w;
                const float s = ((a >> p) & 1) ? zs : -zs;
                const float nr = rx_ * zc - ix_ * s;
                const float ni = rx_ * s + ix_ * zc;
                rx_ = nr; ix_ = ni;
            }
            ar[r] = rx_; ai[r] = ix_;
        }
        // CNOT ring w -> (w+1)%8, sequential (bit P = 7-w)
        cnot_bits<7, 6>(lane, ar, ai);
        cnot_bits<6, 5>(lane, ar, ai);
        cnot_bits<5, 4>(lane, ar, ai);
        cnot_bits<4, 3>(lane, ar, ai);
        cnot_bits<3, 2>(lane, ar, ai);
        cnot_bits<2, 1>(lane, ar, ai);
        cnot_bits<1, 0>(lane, ar, ai);
        cnot_bits<0, 7>(lane, ar, ai);
    }

    // 10 CRX gates: control g%8, target (g+1)%8 (gt ~ N(0,1): small-angle trig)
    float cg[10], sg[10];
    #pragma unroll
    for (int g = 0; g < 10; ++g) {
        cg[g] = cosf(0.5f * gt[g]);
        sg[g] = sinf(0.5f * gt[g]);
    }

    crx_bits<7, 6>(lane, cg[0], sg[0], ar, ai);
    crx_bits<6, 5>(lane, cg[1], sg[1], ar, ai);
    crx_bits<5, 4>(lane, cg[2], sg[2], ar, ai);
    crx_bits<4, 3>(lane, cg[3], sg[3], ar, ai);
    crx_bits<3, 2>(lane, cg[4], sg[4], ar, ai);
    crx_bits<2, 1>(lane, cg[5], sg[5], ar, ai);
    crx_bits<1, 0>(lane, cg[6], sg[6], ar, ai);
    crx_bits<0, 7>(lane, cg[7], sg[7], ar, ai);
    crx_bits<7, 6>(lane, cg[8], sg[8], ar, ai);
    crx_bits<6, 5>(lane, cg[9], sg[9], ar, ai);

    // expectation values: <Z_3> = bit4 of a = lane bit2 ; <Z_7> = bit0 of a = slot bit0
    const float p0 = ar[0] * ar[0] + ai[0] * ai[0];
    const float p1 = ar[1] * ar[1] + ai[1] * ai[1];
    const float p2 = ar[2] * ar[2] + ai[2] * ai[2];
    const float p3 = ar[3] * ar[3] + ai[3] * ai[3];
    float e3 = ((lane >> 2) & 1) ? -(p0 + p1 + p2 + p3) : (p0 + p1 + p2 + p3);
    float e7 = (p0 - p1) + (p2 - p3);
    #pragma unroll
    for (int m = 1; m < 64; m <<= 1) {
        e3 += shflx(e3, m);
        e7 += shflx(e7, m);
    }

    // MLP head (serial on lane 0; round-4 verbatim)
    if (valid && lane == 0) {
        float acc = b2[0];
        #pragma unroll
        for (int j = 0; j < 10; ++j) {
            float h = tanhf(W1[2 * j] * e3 + W1[2 * j + 1] * e7 + b1[j]);
            acc += W2[j] * h;
        }
        out[b] = 1.0f / (1.0f + expf(-acc));
    }
}

extern "C" void kernel_launch(void* const* d_in, const int* in_sizes, int n_in,
                              void* d_out, int out_size, void* d_ws, size_t ws_size,
                              hipStream_t stream) {
    const float* x  = (const float*)d_in[0];
    const float* gt = (const float*)d_in[1];
    const float* W1 = (const float*)d_in[2];
    const float* b1 = (const float*)d_in[3];
    const float* W2 = (const float*)d_in[4];
    const float* b2 = (const float*)d_in[5];
    float* out = (float*)d_out;

    const int Btot = in_sizes[0] / 2;   // x is (B, 2)
    const int blocks = (Btot + 3) / 4;  // 4 waves (batch elements) per 256-thread block

    vqc_reg_kernel<<<blocks, 256, 0, stream>>>(x, gt, W1, b1, W2, b2, out, Btot);
}

// Round 7
// 110.834 us; speedup vs baseline: 1.8577x; 1.4290x over previous
//
#include <hip/hip_runtime.h>
#include <math.h>

// Register-resident VQC simulator. One wave64 per batch element.
// a = (lane<<2) | r ; wire w <-> bit P = 7-w. Bits 7..2 = lane bits 5..0.
// Round-5-verified gate code, plus:
//  - RZ^(x8) as single phase multiply e^{i*phi*(popc(a)-4)}, built by COMPLEX
//    SQUARING from cos/sin(phi/2) — no large-angle trig (that was the r0/2/3 bug).
//  - CRX cos/sin table hoisted to a prep kernel (wave-invariant work).
//  - xor-1/xor-2 lane exchanges via DPP quad_perm (VALU pipe, ~1cy latency)
//    instead of ds_swizzle (~30cy).

template<int CTRL>
__device__ __forceinline__ float dppmov(float v) {
    return __int_as_float(__builtin_amdgcn_update_dpp(
        __float_as_int(v), __float_as_int(v), CTRL, 0xF, 0xF, true));
}

template<int M>
__device__ __forceinline__ float xs(float v) {
    if constexpr (M == 1)      return dppmov<0xB1>(v);   // quad_perm [1,0,3,2]
    else if constexpr (M == 2) return dppmov<0x4E>(v);   // quad_perm [2,3,0,1]
    else                       return __shfl_xor(v, M, 64);
}

// ---- generic 1q RX on amplitude bit P ----
template<int P>
__device__ __forceinline__ void rx_bit(float (&ar)[4], float (&ai)[4],
                                       float ct, float st) {
    if constexpr (P >= 2) {
        constexpr int m = 1 << (P - 2);
        #pragma unroll
        for (int r = 0; r < 4; ++r) {
            float pr = xs<m>(ar[r]), pi = xs<m>(ai[r]);
            float nr = ct * ar[r] + st * pi;
            float ni = ct * ai[r] - st * pr;
            ar[r] = nr; ai[r] = ni;
        }
    } else {
        float nr[4], ni[4];
        #pragma unroll
        for (int r = 0; r < 4; ++r) {
            const int rp = r ^ (1 << P);
            nr[r] = ct * ar[r] + st * ai[rp];
            ni[r] = ct * ai[r] - st * ar[rp];
        }
        #pragma unroll
        for (int r = 0; r < 4; ++r) { ar[r] = nr[r]; ai[r] = ni[r]; }
    }
}

// ---- generic CNOT: control bit PC, target bit PT ----
template<int PC, int PT>
__device__ __forceinline__ void cnot_bits(int lane, float (&ar)[4], float (&ai)[4]) {
    if constexpr (PT >= 2) {
        constexpr int m = 1 << (PT - 2);
        #pragma unroll
        for (int r = 0; r < 4; ++r) {
            bool ctrl;
            if constexpr (PC >= 2) ctrl = (lane >> (PC - 2)) & 1;
            else                   ctrl = (r >> PC) & 1;
            float pr = xs<m>(ar[r]), pi = xs<m>(ai[r]);
            ar[r] = ctrl ? pr : ar[r];
            ai[r] = ctrl ? pi : ai[r];
        }
    } else {
        float nr[4], ni[4];
        #pragma unroll
        for (int r = 0; r < 4; ++r) {
            const int rp = r ^ (1 << PT);
            bool ctrl;
            if constexpr (PC >= 2) ctrl = (lane >> (PC - 2)) & 1;
            else                   ctrl = (r >> PC) & 1;
            nr[r] = ctrl ? ar[rp] : ar[r];
            ni[r] = ctrl ? ai[rp] : ai[r];
        }
        #pragma unroll
        for (int r = 0; r < 4; ++r) { ar[r] = nr[r]; ai[r] = ni[r]; }
    }
}

// ---- generic CRX: control bit PC, target bit PT ----
template<int PC, int PT>
__device__ __forceinline__ void crx_bits(int lane, float c, float s,
                                         float (&ar)[4], float (&ai)[4]) {
    if constexpr (PT >= 2) {
        constexpr int m = 1 << (PT - 2);
        #pragma unroll
        for (int r = 0; r < 4; ++r) {
            bool ctrl;
            if constexpr (PC >= 2) ctrl = (lane >> (PC - 2)) & 1;
            else                   ctrl = (r >> PC) & 1;
            float pr = xs<m>(ar[r]), pi = xs<m>(ai[r]);
            float nr = c * ar[r] + s * pi;
            float ni = c * ai[r] - s * pr;
            ar[r] = ctrl ? nr : ar[r];
            ai[r] = ctrl ? ni : ai[r];
        }
    } else {
        float nr[4], ni[4];
        #pragma unroll
        for (int r = 0; r < 4; ++r) {
            const int rp = r ^ (1 << PT);
            bool ctrl;
            if constexpr (PC >= 2) ctrl = (lane >> (PC - 2)) & 1;
            else                   ctrl = (r >> PC) & 1;
            float vr = c * ar[r] + s * ai[rp];
            float vi = c * ai[r] - s * ar[rp];
            nr[r] = ctrl ? vr : ar[r];
            ni[r] = ctrl ? vi : ai[r];
        }
        #pragma unroll
        for (int r = 0; r < 4; ++r) { ar[r] = nr[r]; ai[r] = ni[r]; }
    }
}

// ---- prep: wave-invariant CRX trig table into workspace ----
__global__ void vqc_prep_kernel(const float* __restrict__ gt, float* __restrict__ cs) {
    const int i = threadIdx.x;
    if (i < 10) {
        cs[i]      = cosf(0.5f * gt[i]);
        cs[10 + i] = sinf(0.5f * gt[i]);
    }
}

__global__ __launch_bounds__(256) void vqc_reg_kernel(
    const float* __restrict__ x,
    const float* __restrict__ gt,
    const float* __restrict__ W1,
    const float* __restrict__ b1,
    const float* __restrict__ W2,
    const float* __restrict__ b2,
    const float* __restrict__ cs,   // 20-float CRX trig table (nullptr -> compute)
    float* __restrict__ out, int Btot)
{
    const int lane = threadIdx.x & 63;
    const int b = blockIdx.x * 4 + (threadIdx.x >> 6);
    const bool valid = (b < Btot);
    const int bb = valid ? b : 0;

    const float theta = x[2 * bb + 0];
    const float phi   = x[2 * bb + 1];

    const float ct = cosf(0.5f * theta);
    const float st = sinf(0.5f * theta);
    const float zc = cosf(0.5f * phi);    // small-angle only
    const float zs = sinf(0.5f * phi);

    // ---- RZ^(x8) phase e^{i*phi*(popc(a)-4)} via complex squaring ----
    // z1 = e^{i phi} by double-angle from (zc, zs); z2 = z1^2; z4 = z2^2.
    const float c1 = zc * zc - zs * zs,  s1 = 2.f * zc * zs;
    const float c2 = c1 * c1 - s1 * s1,  s2 = 2.f * c1 * s1;
    const float c4 = c2 * c2 - s2 * s2,  s4 = 2.f * c2 * s2;
    const int n = __popc(lane) - 4;              // [-4, 2]
    const int mag = n < 0 ? -n : n;              // [0, 4]
    // w = z1^(mag&1) * z2^(mag&2?) * z4^(mag&4?), then conjugate if n<0
    float wr = (mag & 1) ? c1 : 1.f;
    float wi = (mag & 1) ? s1 : 0.f;
    {
        const float mr = (mag & 2) ? c2 : 1.f, mi = (mag & 2) ? s2 : 0.f;
        const float tr = wr * mr - wi * mi;
        wi = wr * mi + wi * mr; wr = tr;
    }
    {
        const float mr = (mag & 4) ? c4 : 1.f, mi = (mag & 4) ? s4 : 0.f;
        const float tr = wr * mr - wi * mi;
        wi = wr * mi + wi * mr; wr = tr;
    }
    wi = (n < 0) ? -wi : wi;
    // slot phases: slot r adds popc(r) = {0,1,1,2}
    const float W0r = wr, W0i = wi;
    const float W1r = wr * c1 - wi * s1,   W1i = wr * s1 + wi * c1;
    const float W2r = W1r * c1 - W1i * s1, W2i = W1r * s1 + W1i * c1;

    float ar[4], ai[4];
    #pragma unroll
    for (int r = 0; r < 4; ++r) { ar[r] = 0.f; ai[r] = 0.f; }
    if (lane == 0) ar[0] = 1.f;

    #pragma unroll 1
    for (int cyc = 0; cyc < 4; ++cyc) {
        // RX on wires 0..7
        rx_bit<7>(ar, ai, ct, st);
        rx_bit<6>(ar, ai, ct, st);
        rx_bit<5>(ar, ai, ct, st);
        rx_bit<4>(ar, ai, ct, st);
        rx_bit<3>(ar, ai, ct, st);
        rx_bit<2>(ar, ai, ct, st);
        rx_bit<1>(ar, ai, ct, st);
        rx_bit<0>(ar, ai, ct, st);
        // fused RZ^(x8): one complex multiply per slot (phases {W0,W1,W1,W2})
        {
            float nr, ni;
            nr = ar[0] * W0r - ai[0] * W0i; ni = ar[0] * W0i + ai[0] * W0r; ar[0] = nr; ai[0] = ni;
            nr = ar[1] * W1r - ai[1] * W1i; ni = ar[1] * W1i + ai[1] * W1r; ar[1] = nr; ai[1] = ni;
            nr = ar[2] * W1r - ai[2] * W1i; ni = ar[2] * W1i + ai[2] * W1r; ar[2] = nr; ai[2] = ni;
            nr = ar[3] * W2r - ai[3] * W2i; ni = ar[3] * W2i + ai[3] * W2r; ar[3] = nr; ai[3] = ni;
        }
        // CNOT ring w -> (w+1)%8, sequential
        cnot_bits<7, 6>(lane, ar, ai);
        cnot_bits<6, 5>(lane, ar, ai);
        cnot_bits<5, 4>(lane, ar, ai);
        cnot_bits<4, 3>(lane, ar, ai);
        cnot_bits<3, 2>(lane, ar, ai);
        cnot_bits<2, 1>(lane, ar, ai);
        cnot_bits<1, 0>(lane, ar, ai);
        cnot_bits<0, 7>(lane, ar, ai);
    }

    // 10 CRX gates: trig from prep table (uniform loads), fallback computes
    float cg[10], sg[10];
    if (cs) {
        #pragma unroll
        for (int g = 0; g < 10; ++g) { cg[g] = cs[g]; sg[g] = cs[10 + g]; }
    } else {
        #pragma unroll
        for (int g = 0; g < 10; ++g) {
            cg[g] = cosf(0.5f * gt[g]);
            sg[g] = sinf(0.5f * gt[g]);
        }
    }

    crx_bits<7, 6>(lane, cg[0], sg[0], ar, ai);
    crx_bits<6, 5>(lane, cg[1], sg[1], ar, ai);
    crx_bits<5, 4>(lane, cg[2], sg[2], ar, ai);
    crx_bits<4, 3>(lane, cg[3], sg[3], ar, ai);
    crx_bits<3, 2>(lane, cg[4], sg[4], ar, ai);
    crx_bits<2, 1>(lane, cg[5], sg[5], ar, ai);
    crx_bits<1, 0>(lane, cg[6], sg[6], ar, ai);
    crx_bits<0, 7>(lane, cg[7], sg[7], ar, ai);
    crx_bits<7, 6>(lane, cg[8], sg[8], ar, ai);
    crx_bits<6, 5>(lane, cg[9], sg[9], ar, ai);

    // expectation values: <Z_3> = lane bit2 ; <Z_7> = slot bit0
    const float p0 = ar[0] * ar[0] + ai[0] * ai[0];
    const float p1 = ar[1] * ar[1] + ai[1] * ai[1];
    const float p2 = ar[2] * ar[2] + ai[2] * ai[2];
    const float p3 = ar[3] * ar[3] + ai[3] * ai[3];
    float e3 = ((lane >> 2) & 1) ? -(p0 + p1 + p2 + p3) : (p0 + p1 + p2 + p3);
    float e7 = (p0 - p1) + (p2 - p3);
    #pragma unroll
    for (int m = 1; m < 64; m <<= 1) {
        e3 += __shfl_xor(e3, m, 64);
        e7 += __shfl_xor(e7, m, 64);
    }

    // MLP head (serial on lane 0; verified)
    if (valid && lane == 0) {
        float acc = b2[0];
        #pragma unroll
        for (int j = 0; j < 10; ++j) {
            float h = tanhf(W1[2 * j] * e3 + W1[2 * j + 1] * e7 + b1[j]);
            acc += W2[j] * h;
        }
        out[b] = 1.0f / (1.0f + expf(-acc));
    }
}

extern "C" void kernel_launch(void* const* d_in, const int* in_sizes, int n_in,
                              void* d_out, int out_size, void* d_ws, size_t ws_size,
                              hipStream_t stream) {
    const float* x  = (const float*)d_in[0];
    const float* gt = (const float*)d_in[1];
    const float* W1 = (const float*)d_in[2];
    const float* b1 = (const float*)d_in[3];
    const float* W2 = (const float*)d_in[4];
    const float* b2 = (const float*)d_in[5];
    float* out = (float*)d_out;

    const int Btot = in_sizes[0] / 2;   // x is (B, 2)
    const int blocks = (Btot + 3) / 4;  // 4 waves (batch elements) per 256-thread block

    float* cs = nullptr;
    if (ws_size >= 20 * sizeof(float)) {
        cs = (float*)d_ws;
        vqc_prep_kernel<<<1, 64, 0, stream>>>(gt, cs);
    }
    vqc_reg_kernel<<<blocks, 256, 0, stream>>>(x, gt, W1, b1, W2, b2, cs, out, Btot);
}

// Round 8
// 92.046 us; speedup vs baseline: 2.2368x; 1.2041x over previous
//
#include <hip/hip_runtime.h>
#include <math.h>

// Register-resident VQC simulator. One wave64 per TWO batch elements (ILP2).
// a = (lane<<2) | r ; wire w <-> bit P = 7-w. Bits 7..2 = lane bits 5..0.
// Round-6-verified gate code, plus:
//  - 5 consecutive lane-lane CNOTs (<7,6>..<3,2>) fused into ONE ds_bpermute
//    per register: composed lane permutation precomputed once (ring repeats).
//  - 2 batch elements per wave: independent chains interleave -> latency hiding.
// RZ phases built by complex squaring from cos/sin(phi/2) — NO large-angle trig
// (large-arg cosf/sinf is broken on this toolchain; bisected rounds 3 vs 4).

template<int CTRL>
__device__ __forceinline__ float dppmov(float v) {
    return __int_as_float(__builtin_amdgcn_update_dpp(
        __float_as_int(v), __float_as_int(v), CTRL, 0xF, 0xF, true));
}

template<int M>
__device__ __forceinline__ float xs(float v) {
    if constexpr (M == 1)      return dppmov<0xB1>(v);   // quad_perm [1,0,3,2]
    else if constexpr (M == 2) return dppmov<0x4E>(v);   // quad_perm [2,3,0,1]
    else                       return __shfl_xor(v, M, 64);
}

__device__ __forceinline__ float bperm(int bp, float v) {
    return __int_as_float(__builtin_amdgcn_ds_bpermute(bp, __float_as_int(v)));
}

// ---- generic 1q RX on amplitude bit P ----
template<int P>
__device__ __forceinline__ void rx_bit(float (&ar)[4], float (&ai)[4],
                                       float ct, float st) {
    if constexpr (P >= 2) {
        constexpr int m = 1 << (P - 2);
        #pragma unroll
        for (int r = 0; r < 4; ++r) {
            float pr = xs<m>(ar[r]), pi = xs<m>(ai[r]);
            float nr = ct * ar[r] + st * pi;
            float ni = ct * ai[r] - st * pr;
            ar[r] = nr; ai[r] = ni;
        }
    } else {
        float nr[4], ni[4];
        #pragma unroll
        for (int r = 0; r < 4; ++r) {
            const int rp = r ^ (1 << P);
            nr[r] = ct * ar[r] + st * ai[rp];
            ni[r] = ct * ai[r] - st * ar[rp];
        }
        #pragma unroll
        for (int r = 0; r < 4; ++r) { ar[r] = nr[r]; ai[r] = ni[r]; }
    }
}

// ---- generic CNOT (used only for the slot-involving ring tail) ----
template<int PC, int PT>
__device__ __forceinline__ void cnot_bits(int lane, float (&ar)[4], float (&ai)[4]) {
    if constexpr (PT >= 2) {
        constexpr int m = 1 << (PT - 2);
        #pragma unroll
        for (int r = 0; r < 4; ++r) {
            bool ctrl;
            if constexpr (PC >= 2) ctrl = (lane >> (PC - 2)) & 1;
            else                   ctrl = (r >> PC) & 1;
            float pr = xs<m>(ar[r]), pi = xs<m>(ai[r]);
            ar[r] = ctrl ? pr : ar[r];
            ai[r] = ctrl ? pi : ai[r];
        }
    } else {
        float nr[4], ni[4];
        #pragma unroll
        for (int r = 0; r < 4; ++r) {
            const int rp = r ^ (1 << PT);
            bool ctrl;
            if constexpr (PC >= 2) ctrl = (lane >> (PC - 2)) & 1;
            else                   ctrl = (r >> PC) & 1;
            nr[r] = ctrl ? ar[rp] : ar[r];
            ni[r] = ctrl ? ai[rp] : ai[r];
        }
        #pragma unroll
        for (int r = 0; r < 4; ++r) { ar[r] = nr[r]; ai[r] = ni[r]; }
    }
}

// ---- generic CRX: control bit PC, target bit PT ----
template<int PC, int PT>
__device__ __forceinline__ void crx_bits(int lane, float c, float s,
                                         float (&ar)[4], float (&ai)[4]) {
    if constexpr (PT >= 2) {
        constexpr int m = 1 << (PT - 2);
        #pragma unroll
        for (int r = 0; r < 4; ++r) {
            bool ctrl;
            if constexpr (PC >= 2) ctrl = (lane >> (PC - 2)) & 1;
            else                   ctrl = (r >> PC) & 1;
            float pr = xs<m>(ar[r]), pi = xs<m>(ai[r]);
            float nr = c * ar[r] + s * pi;
            float ni = c * ai[r] - s * pr;
            ar[r] = ctrl ? nr : ar[r];
            ai[r] = ctrl ? ni : ai[r];
        }
    } else {
        float nr[4], ni[4];
        #pragma unroll
        for (int r = 0; r < 4; ++r) {
            const int rp = r ^ (1 << PT);
            bool ctrl;
            if constexpr (PC >= 2) ctrl = (lane >> (PC - 2)) & 1;
            else                   ctrl = (r >> PC) & 1;
            float vr = c * ar[r] + s * ai[rp];
            float vi = c * ai[r] - s * ar[rp];
            nr[r] = ctrl ? vr : ar[r];
            ni[r] = ctrl ? vi : ai[r];
        }
        #pragma unroll
        for (int r = 0; r < 4; ++r) { ar[r] = nr[r]; ai[r] = ni[r]; }
    }
}

// ---- RZ^(x8) phase set for one element: e^{i*phi*(popc(a)-4)} via squaring ----
struct RzPhases { float W0r, W0i, W1r, W1i, W2r, W2i; };

__device__ __forceinline__ RzPhases make_rz(int lane, float zc, float zs) {
    const float c1 = zc * zc - zs * zs,  s1 = 2.f * zc * zs;
    const float c2 = c1 * c1 - s1 * s1,  s2 = 2.f * c1 * s1;
    const float c4 = c2 * c2 - s2 * s2,  s4 = 2.f * c2 * s2;
    const int n = __popc(lane) - 4;
    const int mag = n < 0 ? -n : n;
    float wr = (mag & 1) ? c1 : 1.f;
    float wi = (mag & 1) ? s1 : 0.f;
    {
        const float mr = (mag & 2) ? c2 : 1.f, mi = (mag & 2) ? s2 : 0.f;
        const float tr = wr * mr - wi * mi;
        wi = wr * mi + wi * mr; wr = tr;
    }
    {
        const float mr = (mag & 4) ? c4 : 1.f, mi = (mag & 4) ? s4 : 0.f;
        const float tr = wr * mr - wi * mi;
        wi = wr * mi + wi * mr; wr = tr;
    }
    wi = (n < 0) ? -wi : wi;
    RzPhases P;
    P.W0r = wr; P.W0i = wi;
    P.W1r = wr * c1 - wi * s1;       P.W1i = wr * s1 + wi * c1;
    P.W2r = P.W1r * c1 - P.W1i * s1; P.W2i = P.W1r * s1 + P.W1i * c1;
    return P;
}

__device__ __forceinline__ void rz_apply(const RzPhases& P,
                                         float (&ar)[4], float (&ai)[4]) {
    float nr, ni;
    nr = ar[0] * P.W0r - ai[0] * P.W0i; ni = ar[0] * P.W0i + ai[0] * P.W0r; ar[0] = nr; ai[0] = ni;
    nr = ar[1] * P.W1r - ai[1] * P.W1i; ni = ar[1] * P.W1i + ai[1] * P.W1r; ar[1] = nr; ai[1] = ni;
    nr = ar[2] * P.W1r - ai[2] * P.W1i; ni = ar[2] * P.W1i + ai[2] * P.W1r; ar[2] = nr; ai[2] = ni;
    nr = ar[3] * P.W2r - ai[3] * P.W2i; ni = ar[3] * P.W2i + ai[3] * P.W2r; ar[3] = nr; ai[3] = ni;
}

// ---- prep: wave-invariant CRX trig table into workspace ----
__global__ void vqc_prep_kernel(const float* __restrict__ gt, float* __restrict__ cs) {
    const int i = threadIdx.x;
    if (i < 10) {
        cs[i]      = cosf(0.5f * gt[i]);
        cs[10 + i] = sinf(0.5f * gt[i]);
    }
}

__global__ __launch_bounds__(256) void vqc_reg_kernel(
    const float* __restrict__ x,
    const float* __restrict__ gt,
    const float* __restrict__ W1,
    const float* __restrict__ b1,
    const float* __restrict__ W2,
    const float* __restrict__ b2,
    const float* __restrict__ cs,
    float* __restrict__ out, int Btot)
{
    const int lane = threadIdx.x & 63;
    const int wid  = blockIdx.x * 4 + (threadIdx.x >> 6);
    const int b0 = 2 * wid, b1i = 2 * wid + 1;
    const int bb0 = b0  < Btot ? b0  : 0;
    const int bb1 = b1i < Btot ? b1i : 0;

    const float2* x2 = (const float2*)x;
    const float2 xv0 = x2[bb0];
    const float2 xv1 = x2[bb1];

    const float ct0 = cosf(0.5f * xv0.x), st0 = sinf(0.5f * xv0.x);
    const float ct1 = cosf(0.5f * xv1.x), st1 = sinf(0.5f * xv1.x);
    const RzPhases RZ0 = make_rz(lane, cosf(0.5f * xv0.y), sinf(0.5f * xv0.y));
    const RzPhases RZ1 = make_rz(lane, cosf(0.5f * xv1.y), sinf(0.5f * xv1.y));

    // Composed lane permutation of the 5 lane-lane CNOTs <7,6>..<3,2>:
    // new[l] = old[s76(s65(s54(s43(s32(l)))))], s_{cb,tm}(l) = l ^ (bit_cb(l)?tm:0).
    // Ring repeats identically every cycle -> compute once.
    int pa = lane;
    pa ^= ((pa >> 1) & 1) << 0;   // s32: cb=1, tm=1
    pa ^= ((pa >> 2) & 1) << 1;   // s43: cb=2, tm=2
    pa ^= ((pa >> 3) & 1) << 2;   // s54: cb=3, tm=4
    pa ^= ((pa >> 4) & 1) << 3;   // s65: cb=4, tm=8
    pa ^= ((pa >> 5) & 1) << 4;   // s76: cb=5, tm=16
    const int bp = pa << 2;

    float ar0[4], ai0[4], ar1[4], ai1[4];
    #pragma unroll
    for (int r = 0; r < 4; ++r) { ar0[r] = ai0[r] = ar1[r] = ai1[r] = 0.f; }
    if (lane == 0) { ar0[0] = 1.f; ar1[0] = 1.f; }

    #pragma unroll 1
    for (int cyc = 0; cyc < 4; ++cyc) {
        // RX on wires 0..7, both elements (independent chains)
        rx_bit<7>(ar0, ai0, ct0, st0);  rx_bit<7>(ar1, ai1, ct1, st1);
        rx_bit<6>(ar0, ai0, ct0, st0);  rx_bit<6>(ar1, ai1, ct1, st1);
        rx_bit<5>(ar0, ai0, ct0, st0);  rx_bit<5>(ar1, ai1, ct1, st1);
        rx_bit<4>(ar0, ai0, ct0, st0);  rx_bit<4>(ar1, ai1, ct1, st1);
        rx_bit<3>(ar0, ai0, ct0, st0);  rx_bit<3>(ar1, ai1, ct1, st1);
        rx_bit<2>(ar0, ai0, ct0, st0);  rx_bit<2>(ar1, ai1, ct1, st1);
        rx_bit<1>(ar0, ai0, ct0, st0);  rx_bit<1>(ar1, ai1, ct1, st1);
        rx_bit<0>(ar0, ai0, ct0, st0);  rx_bit<0>(ar1, ai1, ct1, st1);
        // fused RZ^(x8)
        rz_apply(RZ0, ar0, ai0);
        rz_apply(RZ1, ar1, ai1);
        // CNOT ring: <7,6>..<3,2> fused into one bpermute per register
        #pragma unroll
        for (int r = 0; r < 4; ++r) {
            ar0[r] = bperm(bp, ar0[r]);  ai0[r] = bperm(bp, ai0[r]);
            ar1[r] = bperm(bp, ar1[r]);  ai1[r] = bperm(bp, ai1[r]);
        }
        // ring tail (slot-involving), verified generic templates
        cnot_bits<2, 1>(lane, ar0, ai0);  cnot_bits<2, 1>(lane, ar1, ai1);
        cnot_bits<1, 0>(lane, ar0, ai0);  cnot_bits<1, 0>(lane, ar1, ai1);
        cnot_bits<0, 7>(lane, ar0, ai0);  cnot_bits<0, 7>(lane, ar1, ai1);
    }

    // 10 CRX gates: trig from prep table (wave-uniform), fallback computes
    float cg[10], sg[10];
    if (cs) {
        #pragma unroll
        for (int g = 0; g < 10; ++g) { cg[g] = cs[g]; sg[g] = cs[10 + g]; }
    } else {
        #pragma unroll
        for (int g = 0; g < 10; ++g) {
            cg[g] = cosf(0.5f * gt[g]);
            sg[g] = sinf(0.5f * gt[g]);
        }
    }

    crx_bits<7, 6>(lane, cg[0], sg[0], ar0, ai0);  crx_bits<7, 6>(lane, cg[0], sg[0], ar1, ai1);
    crx_bits<6, 5>(lane, cg[1], sg[1], ar0, ai0);  crx_bits<6, 5>(lane, cg[1], sg[1], ar1, ai1);
    crx_bits<5, 4>(lane, cg[2], sg[2], ar0, ai0);  crx_bits<5, 4>(lane, cg[2], sg[2], ar1, ai1);
    crx_bits<4, 3>(lane, cg[3], sg[3], ar0, ai0);  crx_bits<4, 3>(lane, cg[3], sg[3], ar1, ai1);
    crx_bits<3, 2>(lane, cg[4], sg[4], ar0, ai0);  crx_bits<3, 2>(lane, cg[4], sg[4], ar1, ai1);
    crx_bits<2, 1>(lane, cg[5], sg[5], ar0, ai0);  crx_bits<2, 1>(lane, cg[5], sg[5], ar1, ai1);
    crx_bits<1, 0>(lane, cg[6], sg[6], ar0, ai0);  crx_bits<1, 0>(lane, cg[6], sg[6], ar1, ai1);
    crx_bits<0, 7>(lane, cg[7], sg[7], ar0, ai0);  crx_bits<0, 7>(lane, cg[7], sg[7], ar1, ai1);
    crx_bits<7, 6>(lane, cg[8], sg[8], ar0, ai0);  crx_bits<7, 6>(lane, cg[8], sg[8], ar1, ai1);
    crx_bits<6, 5>(lane, cg[9], sg[9], ar0, ai0);  crx_bits<6, 5>(lane, cg[9], sg[9], ar1, ai1);

    // expectation values: <Z_3> = lane bit2 ; <Z_7> = slot bit0 (per element)
    const float q00 = ar0[0]*ar0[0] + ai0[0]*ai0[0];
    const float q01 = ar0[1]*ar0[1] + ai0[1]*ai0[1];
    const float q02 = ar0[2]*ar0[2] + ai0[2]*ai0[2];
    const float q03 = ar0[3]*ar0[3] + ai0[3]*ai0[3];
    const float q10 = ar1[0]*ar1[0] + ai1[0]*ai1[0];
    const float q11 = ar1[1]*ar1[1] + ai1[1]*ai1[1];
    const float q12 = ar1[2]*ar1[2] + ai1[2]*ai1[2];
    const float q13 = ar1[3]*ar1[3] + ai1[3]*ai1[3];
    const float sgn3 = ((lane >> 2) & 1) ? -1.f : 1.f;
    float e3_0 = sgn3 * (q00 + q01 + q02 + q03);
    float e7_0 = (q00 - q01) + (q02 - q03);
    float e3_1 = sgn3 * (q10 + q11 + q12 + q13);
    float e7_1 = (q10 - q11) + (q12 - q13);
    #pragma unroll
    for (int m = 1; m < 64; m <<= 1) {
        e3_0 += __shfl_xor(e3_0, m, 64);
        e7_0 += __shfl_xor(e7_0, m, 64);
        e3_1 += __shfl_xor(e3_1, m, 64);
        e7_1 += __shfl_xor(e7_1, m, 64);
    }

    // MLP head: lane 0 -> element 0, lane 1 -> element 1 (verified serial form)
    if (lane < 2) {
        const int   bo = lane ? b1i  : b0;
        const float fe3 = lane ? e3_1 : e3_0;
        const float fe7 = lane ? e7_1 : e7_0;
        if (bo < Btot) {
            float acc = b2[0];
            #pragma unroll
            for (int j = 0; j < 10; ++j) {
                float h = tanhf(W1[2 * j] * fe3 + W1[2 * j + 1] * fe7 + b1[j]);
                acc += W2[j] * h;
            }
            out[bo] = 1.0f / (1.0f + expf(-acc));
        }
    }
}

extern "C" void kernel_launch(void* const* d_in, const int* in_sizes, int n_in,
                              void* d_out, int out_size, void* d_ws, size_t ws_size,
                              hipStream_t stream) {
    const float* x  = (const float*)d_in[0];
    const float* gt = (const float*)d_in[1];
    const float* W1 = (const float*)d_in[2];
    const float* b1 = (const float*)d_in[3];
    const float* W2 = (const float*)d_in[4];
    const float* b2 = (const float*)d_in[5];
    float* out = (float*)d_out;

    const int Btot  = in_sizes[0] / 2;          // x is (B, 2)
    const int waves = (Btot + 1) / 2;           // 2 elements per wave
    const int blocks = (waves + 3) / 4;         // 4 waves per 256-thread block

    float* cs = nullptr;
    if (ws_size >= 20 * sizeof(float)) {
        cs = (float*)d_ws;
        vqc_prep_kernel<<<1, 64, 0, stream>>>(gt, cs);
    }
    vqc_reg_kernel<<<blocks, 256, 0, stream>>>(x, gt, W1, b1, W2, b2, cs, out, Btot);
}

// Round 9
// 91.620 us; speedup vs baseline: 2.2473x; 1.0047x over previous
//
#include <hip/hip_runtime.h>
#include <math.h>

// Register-resident VQC simulator. One wave64 per TWO batch elements, PACKED:
// element 0 in .x / element 1 in .y of every float2; all gate arithmetic is
// elementwise v_pk_*_f32 (2x f32 per instruction — required to approach the
// 157 TF fp32 vector peak). Shuffles/selects remain per-b32 (unchanged count).
// a = (lane<<2) | r ; wire w <-> bit P = 7-w. Bits 7..2 = lane bits 5..0.
// 5 lane-lane CNOTs fused into one ds_bpermute (verified round 7).
// RZ phases via complex squaring from cos/sin(phi/2) — NO large-angle trig
// (large-arg cosf/sinf broken on this toolchain; bisected rounds 3 vs 4).

// ---- packed f32 primitives (elementwise; default VOP3P modifiers) ----
__device__ __forceinline__ float2 pk_mul(float2 a, float2 b) {
    float2 d; asm("v_pk_mul_f32 %0, %1, %2" : "=v"(d) : "v"(a), "v"(b)); return d;
}
__device__ __forceinline__ float2 pk_fma(float2 a, float2 b, float2 c) {
    float2 d; asm("v_pk_fma_f32 %0, %1, %2, %3" : "=v"(d) : "v"(a), "v"(b), "v"(c)); return d;
}
__device__ __forceinline__ float2 pk_add(float2 a, float2 b) {
    float2 d; asm("v_pk_add_f32 %0, %1, %2" : "=v"(d) : "v"(a), "v"(b)); return d;
}

template<int CTRL>
__device__ __forceinline__ float dppmov(float v) {
    return __int_as_float(__builtin_amdgcn_update_dpp(
        __float_as_int(v), __float_as_int(v), CTRL, 0xF, 0xF, true));
}

template<int M>
__device__ __forceinline__ float xs(float v) {
    if constexpr (M == 1)      return dppmov<0xB1>(v);   // quad_perm [1,0,3,2]
    else if constexpr (M == 2) return dppmov<0x4E>(v);   // quad_perm [2,3,0,1]
    else                       return __shfl_xor(v, M, 64);
}

template<int M>
__device__ __forceinline__ float2 xs2(float2 v) {
    return make_float2(xs<M>(v.x), xs<M>(v.y));
}

__device__ __forceinline__ float2 bperm2(int bp, float2 v) {
    return make_float2(
        __int_as_float(__builtin_amdgcn_ds_bpermute(bp, __float_as_int(v.x))),
        __int_as_float(__builtin_amdgcn_ds_bpermute(bp, __float_as_int(v.y))));
}

__device__ __forceinline__ float2 sel2(bool c, float2 a, float2 b) {
    return make_float2(c ? a.x : b.x, c ? a.y : b.y);
}

// ---- generic 1q RX on amplitude bit P (packed) ----
template<int P>
__device__ __forceinline__ void rx_bit_pk(float2 (&AR)[4], float2 (&AI)[4],
                                          float2 CT, float2 ST, float2 NST) {
    if constexpr (P >= 2) {
        constexpr int m = 1 << (P - 2);
        #pragma unroll
        for (int r = 0; r < 4; ++r) {
            float2 PR = xs2<m>(AR[r]), PI = xs2<m>(AI[r]);
            AR[r] = pk_fma(CT, AR[r], pk_mul(ST, PI));    // ct*ar + st*pi
            AI[r] = pk_fma(CT, AI[r], pk_mul(NST, PR));   // ct*ai - st*pr
        }
    } else {
        float2 NR[4], NI[4];
        #pragma unroll
        for (int r = 0; r < 4; ++r) {
            const int rp = r ^ (1 << P);
            NR[r] = pk_fma(CT, AR[r], pk_mul(ST, AI[rp]));
            NI[r] = pk_fma(CT, AI[r], pk_mul(NST, AR[rp]));
        }
        #pragma unroll
        for (int r = 0; r < 4; ++r) { AR[r] = NR[r]; AI[r] = NI[r]; }
    }
}

// ---- generic CNOT (slot-involving ring tail) ----
template<int PC, int PT>
__device__ __forceinline__ void cnot_bits_pk(int lane, float2 (&AR)[4], float2 (&AI)[4]) {
    if constexpr (PT >= 2) {
        constexpr int m = 1 << (PT - 2);
        #pragma unroll
        for (int r = 0; r < 4; ++r) {
            bool ctrl;
            if constexpr (PC >= 2) ctrl = (lane >> (PC - 2)) & 1;
            else                   ctrl = (r >> PC) & 1;
            float2 PR = xs2<m>(AR[r]), PI = xs2<m>(AI[r]);
            AR[r] = sel2(ctrl, PR, AR[r]);
            AI[r] = sel2(ctrl, PI, AI[r]);
        }
    } else {
        float2 NR[4], NI[4];
        #pragma unroll
        for (int r = 0; r < 4; ++r) {
            const int rp = r ^ (1 << PT);
            bool ctrl;
            if constexpr (PC >= 2) ctrl = (lane >> (PC - 2)) & 1;
            else                   ctrl = (r >> PC) & 1;
            NR[r] = sel2(ctrl, AR[rp], AR[r]);
            NI[r] = sel2(ctrl, AI[rp], AI[r]);
        }
        #pragma unroll
        for (int r = 0; r < 4; ++r) { AR[r] = NR[r]; AI[r] = NI[r]; }
    }
}

// ---- generic CRX: control bit PC, target bit PT (packed; c,s wave-uniform) ----
template<int PC, int PT>
__device__ __forceinline__ void crx_bits_pk(int lane, float c, float s,
                                            float2 (&AR)[4], float2 (&AI)[4]) {
    const float2 C  = make_float2(c, c);
    const float2 S  = make_float2(s, s);
    const float2 NS = make_float2(-s, -s);
    if constexpr (PT >= 2) {
        constexpr int m = 1 << (PT - 2);
        #pragma unroll
        for (int r = 0; r < 4; ++r) {
            bool ctrl;
            if constexpr (PC >= 2) ctrl = (lane >> (PC - 2)) & 1;
            else                   ctrl = (r >> PC) & 1;
            float2 PR = xs2<m>(AR[r]), PI = xs2<m>(AI[r]);
            float2 NRv = pk_fma(C, AR[r], pk_mul(S, PI));
            float2 NIv = pk_fma(C, AI[r], pk_mul(NS, PR));
            AR[r] = sel2(ctrl, NRv, AR[r]);
            AI[r] = sel2(ctrl, NIv, AI[r]);
        }
    } else {
        float2 NR[4], NI[4];
        #pragma unroll
        for (int r = 0; r < 4; ++r) {
            const int rp = r ^ (1 << PT);
            bool ctrl;
            if constexpr (PC >= 2) ctrl = (lane >> (PC - 2)) & 1;
            else                   ctrl = (r >> PC) & 1;
            float2 VR = pk_fma(C, AR[r], pk_mul(S, AI[rp]));
            float2 VI = pk_fma(C, AI[r], pk_mul(NS, AR[rp]));
            NR[r] = sel2(ctrl, VR, AR[r]);
            NI[r] = sel2(ctrl, VI, AI[r]);
        }
        #pragma unroll
        for (int r = 0; r < 4; ++r) { AR[r] = NR[r]; AI[r] = NI[r]; }
    }
}

// ---- RZ^(x8) phases per element: e^{i*phi*(popc(a)-4)} via complex squaring ----
struct RzPhases { float W0r, W0i, W1r, W1i, W2r, W2i; };

__device__ __forceinline__ RzPhases make_rz(int lane, float zc, float zs) {
    const float c1 = zc * zc - zs * zs,  s1 = 2.f * zc * zs;
    const float c2 = c1 * c1 - s1 * s1,  s2 = 2.f * c1 * s1;
    const float c4 = c2 * c2 - s2 * s2,  s4 = 2.f * c2 * s2;
    const int n = __popc(lane) - 4;
    const int mag = n < 0 ? -n : n;
    float wr = (mag & 1) ? c1 : 1.f;
    float wi = (mag & 1) ? s1 : 0.f;
    {
        const float mr = (mag & 2) ? c2 : 1.f, mi = (mag & 2) ? s2 : 0.f;
        const float tr = wr * mr - wi * mi;
        wi = wr * mi + wi * mr; wr = tr;
    }
    {
        const float mr = (mag & 4) ? c4 : 1.f, mi = (mag & 4) ? s4 : 0.f;
        const float tr = wr * mr - wi * mi;
        wi = wr * mi + wi * mr; wr = tr;
    }
    wi = (n < 0) ? -wi : wi;
    RzPhases P;
    P.W0r = wr; P.W0i = wi;
    P.W1r = wr * c1 - wi * s1;       P.W1i = wr * s1 + wi * c1;
    P.W2r = P.W1r * c1 - P.W1i * s1; P.W2i = P.W1r * s1 + P.W1i * c1;
    return P;
}

// ---- prep: wave-invariant CRX trig table into workspace ----
__global__ void vqc_prep_kernel(const float* __restrict__ gt, float* __restrict__ cs) {
    const int i = threadIdx.x;
    if (i < 10) {
        cs[i]      = cosf(0.5f * gt[i]);
        cs[10 + i] = sinf(0.5f * gt[i]);
    }
}

__global__ __launch_bounds__(256) void vqc_reg_kernel(
    const float* __restrict__ x,
    const float* __restrict__ gt,
    const float* __restrict__ W1,
    const float* __restrict__ b1,
    const float* __restrict__ W2,
    const float* __restrict__ b2,
    const float* __restrict__ cs,
    float* __restrict__ out, int Btot)
{
    const int lane = threadIdx.x & 63;
    const int wid  = blockIdx.x * 4 + (threadIdx.x >> 6);
    const int b0 = 2 * wid, b1i = 2 * wid + 1;
    const int bb0 = b0  < Btot ? b0  : 0;
    const int bb1 = b1i < Btot ? b1i : 0;

    const float2* x2 = (const float2*)x;
    const float2 xv0 = x2[bb0];
    const float2 xv1 = x2[bb1];

    const float2 CT  = make_float2(cosf(0.5f * xv0.x),  cosf(0.5f * xv1.x));
    const float2 ST  = make_float2(sinf(0.5f * xv0.x),  sinf(0.5f * xv1.x));
    const float2 NST = make_float2(-ST.x, -ST.y);

    const RzPhases Z0 = make_rz(lane, cosf(0.5f * xv0.y), sinf(0.5f * xv0.y));
    const RzPhases Z1 = make_rz(lane, cosf(0.5f * xv1.y), sinf(0.5f * xv1.y));
    const float2 W0R = make_float2(Z0.W0r, Z1.W0r), W0I = make_float2(Z0.W0i, Z1.W0i);
    const float2 W1R = make_float2(Z0.W1r, Z1.W1r), W1I = make_float2(Z0.W1i, Z1.W1i);
    const float2 W2R = make_float2(Z0.W2r, Z1.W2r), W2I = make_float2(Z0.W2i, Z1.W2i);
    const float2 NW0I = make_float2(-W0I.x, -W0I.y);
    const float2 NW1I = make_float2(-W1I.x, -W1I.y);
    const float2 NW2I = make_float2(-W2I.x, -W2I.y);

    // Composed lane permutation of the 5 lane-lane CNOTs <7,6>..<3,2> (verified r7)
    int pa = lane;
    pa ^= ((pa >> 1) & 1) << 0;
    pa ^= ((pa >> 2) & 1) << 1;
    pa ^= ((pa >> 3) & 1) << 2;
    pa ^= ((pa >> 4) & 1) << 3;
    pa ^= ((pa >> 5) & 1) << 4;
    const int bp = pa << 2;

    float2 AR[4], AI[4];
    #pragma unroll
    for (int r = 0; r < 4; ++r) { AR[r] = make_float2(0.f, 0.f); AI[r] = make_float2(0.f, 0.f); }
    if (lane == 0) AR[0] = make_float2(1.f, 1.f);

    #pragma unroll 1
    for (int cyc = 0; cyc < 4; ++cyc) {
        rx_bit_pk<7>(AR, AI, CT, ST, NST);
        rx_bit_pk<6>(AR, AI, CT, ST, NST);
        rx_bit_pk<5>(AR, AI, CT, ST, NST);
        rx_bit_pk<4>(AR, AI, CT, ST, NST);
        rx_bit_pk<3>(AR, AI, CT, ST, NST);
        rx_bit_pk<2>(AR, AI, CT, ST, NST);
        rx_bit_pk<1>(AR, AI, CT, ST, NST);
        rx_bit_pk<0>(AR, AI, CT, ST, NST);
        // fused RZ^(x8): slot phases {W0, W1, W1, W2}
        {
            float2 nr, ni;
            nr = pk_fma(AR[0], W0R, pk_mul(AI[0], NW0I)); ni = pk_fma(AR[0], W0I, pk_mul(AI[0], W0R)); AR[0] = nr; AI[0] = ni;
            nr = pk_fma(AR[1], W1R, pk_mul(AI[1], NW1I)); ni = pk_fma(AR[1], W1I, pk_mul(AI[1], W1R)); AR[1] = nr; AI[1] = ni;
            nr = pk_fma(AR[2], W1R, pk_mul(AI[2], NW1I)); ni = pk_fma(AR[2], W1I, pk_mul(AI[2], W1R)); AR[2] = nr; AI[2] = ni;
            nr = pk_fma(AR[3], W2R, pk_mul(AI[3], NW2I)); ni = pk_fma(AR[3], W2I, pk_mul(AI[3], W2R)); AR[3] = nr; AI[3] = ni;
        }
        // CNOT ring head: one bpermute per b32
        #pragma unroll
        for (int r = 0; r < 4; ++r) {
            AR[r] = bperm2(bp, AR[r]);
            AI[r] = bperm2(bp, AI[r]);
        }
        // ring tail (slot-involving)
        cnot_bits_pk<2, 1>(lane, AR, AI);
        cnot_bits_pk<1, 0>(lane, AR, AI);
        cnot_bits_pk<0, 7>(lane, AR, AI);
    }

    // 10 CRX gates: trig from prep table (wave-uniform -> SGPRs)
    float cg[10], sg[10];
    if (cs) {
        #pragma unroll
        for (int g = 0; g < 10; ++g) { cg[g] = cs[g]; sg[g] = cs[10 + g]; }
    } else {
        #pragma unroll
        for (int g = 0; g < 10; ++g) {
            cg[g] = cosf(0.5f * gt[g]);
            sg[g] = sinf(0.5f * gt[g]);
        }
    }

    crx_bits_pk<7, 6>(lane, cg[0], sg[0], AR, AI);
    crx_bits_pk<6, 5>(lane, cg[1], sg[1], AR, AI);
    crx_bits_pk<5, 4>(lane, cg[2], sg[2], AR, AI);
    crx_bits_pk<4, 3>(lane, cg[3], sg[3], AR, AI);
    crx_bits_pk<3, 2>(lane, cg[4], sg[4], AR, AI);
    crx_bits_pk<2, 1>(lane, cg[5], sg[5], AR, AI);
    crx_bits_pk<1, 0>(lane, cg[6], sg[6], AR, AI);
    crx_bits_pk<0, 7>(lane, cg[7], sg[7], AR, AI);
    crx_bits_pk<7, 6>(lane, cg[8], sg[8], AR, AI);
    crx_bits_pk<6, 5>(lane, cg[9], sg[9], AR, AI);

    // probabilities (packed), then verified scalar tail
    const float2 P0 = pk_fma(AR[0], AR[0], pk_mul(AI[0], AI[0]));
    const float2 P1 = pk_fma(AR[1], AR[1], pk_mul(AI[1], AI[1]));
    const float2 P2 = pk_fma(AR[2], AR[2], pk_mul(AI[2], AI[2]));
    const float2 P3 = pk_fma(AR[3], AR[3], pk_mul(AI[3], AI[3]));
    const float q00 = P0.x, q01 = P1.x, q02 = P2.x, q03 = P3.x;
    const float q10 = P0.y, q11 = P1.y, q12 = P2.y, q13 = P3.y;
    const float sgn3 = ((lane >> 2) & 1) ? -1.f : 1.f;
    float e3_0 = sgn3 * (q00 + q01 + q02 + q03);
    float e7_0 = (q00 - q01) + (q02 - q03);
    float e3_1 = sgn3 * (q10 + q11 + q12 + q13);
    float e7_1 = (q10 - q11) + (q12 - q13);
    #pragma unroll
    for (int m = 1; m < 64; m <<= 1) {
        e3_0 += __shfl_xor(e3_0, m, 64);
        e7_0 += __shfl_xor(e7_0, m, 64);
        e3_1 += __shfl_xor(e3_1, m, 64);
        e7_1 += __shfl_xor(e7_1, m, 64);
    }

    // MLP head: lane 0 -> element 0, lane 1 -> element 1 (verified serial form)
    if (lane < 2) {
        const int   bo  = lane ? b1i  : b0;
        const float fe3 = lane ? e3_1 : e3_0;
        const float fe7 = lane ? e7_1 : e7_0;
        if (bo < Btot) {
            float acc = b2[0];
            #pragma unroll
            for (int j = 0; j < 10; ++j) {
                float h = tanhf(W1[2 * j] * fe3 + W1[2 * j + 1] * fe7 + b1[j]);
                acc += W2[j] * h;
            }
            out[bo] = 1.0f / (1.0f + expf(-acc));
        }
    }
}

extern "C" void kernel_launch(void* const* d_in, const int* in_sizes, int n_in,
                              void* d_out, int out_size, void* d_ws, size_t ws_size,
                              hipStream_t stream) {
    const float* x  = (const float*)d_in[0];
    const float* gt = (const float*)d_in[1];
    const float* W1 = (const float*)d_in[2];
    const float* b1 = (const float*)d_in[3];
    const float* W2 = (const float*)d_in[4];
    const float* b2 = (const float*)d_in[5];
    float* out = (float*)d_out;

    const int Btot  = in_sizes[0] / 2;          // x is (B, 2)
    const int waves = (Btot + 1) / 2;           // 2 elements per wave (packed)
    const int blocks = (waves + 3) / 4;         // 4 waves per 256-thread block

    float* cs = nullptr;
    if (ws_size >= 20 * sizeof(float)) {
        cs = (float*)d_ws;
        vqc_prep_kernel<<<1, 64, 0, stream>>>(gt, cs);
    }
    vqc_reg_kernel<<<blocks, 256, 0, stream>>>(x, gt, W1, b1, W2, b2, cs, out, Btot);
}

// Round 11
// 79.016 us; speedup vs baseline: 2.6057x; 1.1595x over previous
//
#include <hip/hip_runtime.h>
#include <math.h>

// Register-resident VQC simulator. One wave64 per TWO batch elements, PACKED
// (elem0 = .x, elem1 = .y of every float2; v_pk_*_f32 arithmetic).
// a = (lane<<2) | r ; wire w <-> bit P = 7-w. Bits 7..2 = lane bits 5..0.
//
// Lane exchanges (DS-pipe was saturated at ~500 wave64 DS ops; move to VALU):
//   xor-1/2 : DPP quad_perm builtin     (verified r6-r8)
//   xor-8   : DPP row_ror:8 builtin     (rotate-8 over 16 == xor-8, exact)
//   xor-16  : __builtin_amdgcn_permlane16_swap + probed select
//   xor-32  : __builtin_amdgcn_permlane32_swap + probed select
//   xor-4   : ds_swizzle (no VALU form); fused-CNOT ds_bpermute stays DS.
// Round-9 LESSON: raw inline-asm permlane swaps read stale registers (DPP-class
// hazard wait-states are NOT inserted around asm blobs) -> builtins only.
// The probe makes the d/s select orientation self-discovering.
// RZ phases via complex squaring from cos/sin(phi/2) — NO large-angle trig
// (large-arg cosf/sinf broken on this toolchain; bisected rounds 3 vs 4).

struct Ex { int lane; bool p16d; bool p32d; };

// ---- packed f32 primitives ----
__device__ __forceinline__ float2 pk_mul(float2 a, float2 b) {
    float2 d; asm("v_pk_mul_f32 %0, %1, %2" : "=v"(d) : "v"(a), "v"(b)); return d;
}
__device__ __forceinline__ float2 pk_fma(float2 a, float2 b, float2 c) {
    float2 d; asm("v_pk_fma_f32 %0, %1, %2, %3" : "=v"(d) : "v"(a), "v"(b), "v"(c)); return d;
}

template<int CTRL>
__device__ __forceinline__ float dppmov(float v) {
    return __int_as_float(__builtin_amdgcn_update_dpp(
        __float_as_int(v), __float_as_int(v), CTRL, 0xF, 0xF, true));
}

// ---- lane xor exchange, VALU where possible ----
template<int M>
__device__ __forceinline__ float xs(float v, const Ex& ex) {
    if constexpr (M == 1)       return dppmov<0xB1>(v);    // quad_perm [1,0,3,2]
    else if constexpr (M == 2)  return dppmov<0x4E>(v);    // quad_perm [2,3,0,1]
    else if constexpr (M == 8)  return dppmov<0x128>(v);   // row_ror:8 == xor-8
    else if constexpr (M == 16) {
#if __has_builtin(__builtin_amdgcn_permlane16_swap)
        auto r = __builtin_amdgcn_permlane16_swap(__float_as_uint(v), __float_as_uint(v),
                                                  false, false);
        return __uint_as_float(ex.p16d ? r[0] : r[1]);
#else
        return __shfl_xor(v, 16, 64);
#endif
    } else if constexpr (M == 32) {
#if __has_builtin(__builtin_amdgcn_permlane32_swap)
        auto r = __builtin_amdgcn_permlane32_swap(__float_as_uint(v), __float_as_uint(v),
                                                  false, false);
        return __uint_as_float(ex.p32d ? r[0] : r[1]);
#else
        return __shfl_xor(v, 32, 64);
#endif
    } else {
        return __shfl_xor(v, M, 64);                       // M==4: ds_swizzle
    }
}

template<int M>
__device__ __forceinline__ float2 xs2(float2 v, const Ex& ex) {
    return make_float2(xs<M>(v.x, ex), xs<M>(v.y, ex));
}

__device__ __forceinline__ float2 bperm2(int bp, float2 v) {
    return make_float2(
        __int_as_float(__builtin_amdgcn_ds_bpermute(bp, __float_as_int(v.x))),
        __int_as_float(__builtin_amdgcn_ds_bpermute(bp, __float_as_int(v.y))));
}

__device__ __forceinline__ float2 sel2(bool c, float2 a, float2 b) {
    return make_float2(c ? a.x : b.x, c ? a.y : b.y);
}

// ---- generic 1q RX on amplitude bit P (packed) ----
template<int P>
__device__ __forceinline__ void rx_bit_pk(const Ex& ex, float2 (&AR)[4], float2 (&AI)[4],
                                          float2 CT, float2 ST, float2 NST) {
    if constexpr (P >= 2) {
        constexpr int m = 1 << (P - 2);
        #pragma unroll
        for (int r = 0; r < 4; ++r) {
            float2 PR = xs2<m>(AR[r], ex), PI = xs2<m>(AI[r], ex);
            AR[r] = pk_fma(CT, AR[r], pk_mul(ST, PI));    // ct*ar + st*pi
            AI[r] = pk_fma(CT, AI[r], pk_mul(NST, PR));   // ct*ai - st*pr
        }
    } else {
        float2 NR[4], NI[4];
        #pragma unroll
        for (int r = 0; r < 4; ++r) {
            const int rp = r ^ (1 << P);
            NR[r] = pk_fma(CT, AR[r], pk_mul(ST, AI[rp]));
            NI[r] = pk_fma(CT, AI[r], pk_mul(NST, AR[rp]));
        }
        #pragma unroll
        for (int r = 0; r < 4; ++r) { AR[r] = NR[r]; AI[r] = NI[r]; }
    }
}

// ---- generic CNOT (slot-involving ring tail) ----
template<int PC, int PT>
__device__ __forceinline__ void cnot_bits_pk(const Ex& ex, float2 (&AR)[4], float2 (&AI)[4]) {
    if constexpr (PT >= 2) {
        constexpr int m = 1 << (PT - 2);
        #pragma unroll
        for (int r = 0; r < 4; ++r) {
            bool ctrl;
            if constexpr (PC >= 2) ctrl = (ex.lane >> (PC - 2)) & 1;
            else                   ctrl = (r >> PC) & 1;
            float2 PR = xs2<m>(AR[r], ex), PI = xs2<m>(AI[r], ex);
            AR[r] = sel2(ctrl, PR, AR[r]);
            AI[r] = sel2(ctrl, PI, AI[r]);
        }
    } else {
        float2 NR[4], NI[4];
        #pragma unroll
        for (int r = 0; r < 4; ++r) {
            const int rp = r ^ (1 << PT);
            bool ctrl;
            if constexpr (PC >= 2) ctrl = (ex.lane >> (PC - 2)) & 1;
            else                   ctrl = (r >> PC) & 1;
            NR[r] = sel2(ctrl, AR[rp], AR[r]);
            NI[r] = sel2(ctrl, AI[rp], AI[r]);
        }
        #pragma unroll
        for (int r = 0; r < 4; ++r) { AR[r] = NR[r]; AI[r] = NI[r]; }
    }
}

// ---- generic CRX: control bit PC, target bit PT (packed; c,s wave-uniform) ----
template<int PC, int PT>
__device__ __forceinline__ void crx_bits_pk(const Ex& ex, float c, float s,
                                            float2 (&AR)[4], float2 (&AI)[4]) {
    const float2 C  = make_float2(c, c);
    const float2 S  = make_float2(s, s);
    const float2 NS = make_float2(-s, -s);
    if constexpr (PT >= 2) {
        constexpr int m = 1 << (PT - 2);
        #pragma unroll
        for (int r = 0; r < 4; ++r) {
            bool ctrl;
            if constexpr (PC >= 2) ctrl = (ex.lane >> (PC - 2)) & 1;
            else                   ctrl = (r >> PC) & 1;
            float2 PR = xs2<m>(AR[r], ex), PI = xs2<m>(AI[r], ex);
            float2 NRv = pk_fma(C, AR[r], pk_mul(S, PI));
            float2 NIv = pk_fma(C, AI[r], pk_mul(NS, PR));
            AR[r] = sel2(ctrl, NRv, AR[r]);
            AI[r] = sel2(ctrl, NIv, AI[r]);
        }
    } else {
        float2 NR[4], NI[4];
        #pragma unroll
        for (int r = 0; r < 4; ++r) {
            const int rp = r ^ (1 << PT);
            bool ctrl;
            if constexpr (PC >= 2) ctrl = (ex.lane >> (PC - 2)) & 1;
            else                   ctrl = (r >> PC) & 1;
            float2 VR = pk_fma(C, AR[r], pk_mul(S, AI[rp]));
            float2 VI = pk_fma(C, AI[r], pk_mul(NS, AR[rp]));
            NR[r] = sel2(ctrl, VR, AR[r]);
            NI[r] = sel2(ctrl, VI, AI[r]);
        }
        #pragma unroll
        for (int r = 0; r < 4; ++r) { AR[r] = NR[r]; AI[r] = NI[r]; }
    }
}

// ---- wave-64 butterfly sum ----
__device__ __forceinline__ float wave_sum(float v, const Ex& ex) {
    v += xs<1>(v, ex);
    v += xs<2>(v, ex);
    v += xs<4>(v, ex);
    v += xs<8>(v, ex);
    v += xs<16>(v, ex);
    v += xs<32>(v, ex);
    return v;
}

// ---- RZ^(x8) phases per element: e^{i*phi*(popc(a)-4)} via complex squaring ----
struct RzPhases { float W0r, W0i, W1r, W1i, W2r, W2i; };

__device__ __forceinline__ RzPhases make_rz(int lane, float zc, float zs) {
    const float c1 = zc * zc - zs * zs,  s1 = 2.f * zc * zs;
    const float c2 = c1 * c1 - s1 * s1,  s2 = 2.f * c1 * s1;
    const float c4 = c2 * c2 - s2 * s2,  s4 = 2.f * c2 * s2;
    const int n = __popc(lane) - 4;
    const int mag = n < 0 ? -n : n;
    float wr = (mag & 1) ? c1 : 1.f;
    float wi = (mag & 1) ? s1 : 0.f;
    {
        const float mr = (mag & 2) ? c2 : 1.f, mi = (mag & 2) ? s2 : 0.f;
        const float tr = wr * mr - wi * mi;
        wi = wr * mi + wi * mr; wr = tr;
    }
    {
        const float mr = (mag & 4) ? c4 : 1.f, mi = (mag & 4) ? s4 : 0.f;
        const float tr = wr * mr - wi * mi;
        wi = wr * mi + wi * mr; wr = tr;
    }
    wi = (n < 0) ? -wi : wi;
    RzPhases P;
    P.W0r = wr; P.W0i = wi;
    P.W1r = wr * c1 - wi * s1;       P.W1i = wr * s1 + wi * c1;
    P.W2r = P.W1r * c1 - P.W1i * s1; P.W2i = P.W1r * s1 + P.W1i * c1;
    return P;
}

// ---- prep: wave-invariant CRX trig table into workspace ----
__global__ void vqc_prep_kernel(const float* __restrict__ gt, float* __restrict__ cs) {
    const int i = threadIdx.x;
    if (i < 10) {
        cs[i]      = cosf(0.5f * gt[i]);
        cs[10 + i] = sinf(0.5f * gt[i]);
    }
}

__global__ __launch_bounds__(256) void vqc_reg_kernel(
    const float* __restrict__ x,
    const float* __restrict__ gt,
    const float* __restrict__ W1,
    const float* __restrict__ b1,
    const float* __restrict__ W2,
    const float* __restrict__ b2,
    const float* __restrict__ cs,
    float* __restrict__ out, int Btot)
{
    const int lane = threadIdx.x & 63;
    const int wid  = blockIdx.x * 4 + (threadIdx.x >> 6);
    const int b0 = 2 * wid, b1i = 2 * wid + 1;
    const int bb0 = b0  < Btot ? b0  : 0;
    const int bb1 = b1i < Btot ? b1i : 0;

    // ---- exchange context: probe the permlane-swap output orientation ----
    Ex ex; ex.lane = lane; ex.p16d = true; ex.p32d = true;
#if __has_builtin(__builtin_amdgcn_permlane16_swap)
    {
        auto pr = __builtin_amdgcn_permlane16_swap((unsigned)lane, (unsigned)lane,
                                                   false, false);
        ex.p16d = (pr[0] == (unsigned)(lane ^ 16));
    }
#endif
#if __has_builtin(__builtin_amdgcn_permlane32_swap)
    {
        auto pr = __builtin_amdgcn_permlane32_swap((unsigned)lane, (unsigned)lane,
                                                   false, false);
        ex.p32d = (pr[0] == (unsigned)(lane ^ 32));
    }
#endif

    const float2* x2 = (const float2*)x;
    const float2 xv0 = x2[bb0];
    const float2 xv1 = x2[bb1];

    const float2 CT  = make_float2(cosf(0.5f * xv0.x),  cosf(0.5f * xv1.x));
    const float2 ST  = make_float2(sinf(0.5f * xv0.x),  sinf(0.5f * xv1.x));
    const float2 NST = make_float2(-ST.x, -ST.y);

    const RzPhases Z0 = make_rz(lane, cosf(0.5f * xv0.y), sinf(0.5f * xv0.y));
    const RzPhases Z1 = make_rz(lane, cosf(0.5f * xv1.y), sinf(0.5f * xv1.y));
    const float2 W0R = make_float2(Z0.W0r, Z1.W0r), W0I = make_float2(Z0.W0i, Z1.W0i);
    const float2 W1R = make_float2(Z0.W1r, Z1.W1r), W1I = make_float2(Z0.W1i, Z1.W1i);
    const float2 W2R = make_float2(Z0.W2r, Z1.W2r), W2I = make_float2(Z0.W2i, Z1.W2i);
    const float2 NW0I = make_float2(-W0I.x, -W0I.y);
    const float2 NW1I = make_float2(-W1I.x, -W1I.y);
    const float2 NW2I = make_float2(-W2I.x, -W2I.y);

    // Composed lane permutation of the 5 lane-lane CNOTs <7,6>..<3,2> (verified r7)
    int pa = lane;
    pa ^= ((pa >> 1) & 1) << 0;
    pa ^= ((pa >> 2) & 1) << 1;
    pa ^= ((pa >> 3) & 1) << 2;
    pa ^= ((pa >> 4) & 1) << 3;
    pa ^= ((pa >> 5) & 1) << 4;
    const int bp = pa << 2;

    float2 AR[4], AI[4];
    #pragma unroll
    for (int r = 0; r < 4; ++r) { AR[r] = make_float2(0.f, 0.f); AI[r] = make_float2(0.f, 0.f); }
    if (lane == 0) AR[0] = make_float2(1.f, 1.f);

    #pragma unroll 1
    for (int cyc = 0; cyc < 4; ++cyc) {
        rx_bit_pk<7>(ex, AR, AI, CT, ST, NST);
        rx_bit_pk<6>(ex, AR, AI, CT, ST, NST);
        rx_bit_pk<5>(ex, AR, AI, CT, ST, NST);
        rx_bit_pk<4>(ex, AR, AI, CT, ST, NST);
        rx_bit_pk<3>(ex, AR, AI, CT, ST, NST);
        rx_bit_pk<2>(ex, AR, AI, CT, ST, NST);
        rx_bit_pk<1>(ex, AR, AI, CT, ST, NST);
        rx_bit_pk<0>(ex, AR, AI, CT, ST, NST);
        // fused RZ^(x8): slot phases {W0, W1, W1, W2}
        {
            float2 nr, ni;
            nr = pk_fma(AR[0], W0R, pk_mul(AI[0], NW0I)); ni = pk_fma(AR[0], W0I, pk_mul(AI[0], W0R)); AR[0] = nr; AI[0] = ni;
            nr = pk_fma(AR[1], W1R, pk_mul(AI[1], NW1I)); ni = pk_fma(AR[1], W1I, pk_mul(AI[1], W1R)); AR[1] = nr; AI[1] = ni;
            nr = pk_fma(AR[2], W1R, pk_mul(AI[2], NW1I)); ni = pk_fma(AR[2], W1I, pk_mul(AI[2], W1R)); AR[2] = nr; AI[2] = ni;
            nr = pk_fma(AR[3], W2R, pk_mul(AI[3], NW2I)); ni = pk_fma(AR[3], W2I, pk_mul(AI[3], W2R)); AR[3] = nr; AI[3] = ni;
        }
        // CNOT ring head: one bpermute per b32
        #pragma unroll
        for (int r = 0; r < 4; ++r) {
            AR[r] = bperm2(bp, AR[r]);
            AI[r] = bperm2(bp, AI[r]);
        }
        // ring tail (slot-involving)
        cnot_bits_pk<2, 1>(ex, AR, AI);
        cnot_bits_pk<1, 0>(ex, AR, AI);
        cnot_bits_pk<0, 7>(ex, AR, AI);
    }

    // 10 CRX gates: trig from prep table (wave-uniform)
    float cg[10], sg[10];
    if (cs) {
        #pragma unroll
        for (int g = 0; g < 10; ++g) { cg[g] = cs[g]; sg[g] = cs[10 + g]; }
    } else {
        #pragma unroll
        for (int g = 0; g < 10; ++g) {
            cg[g] = cosf(0.5f * gt[g]);
            sg[g] = sinf(0.5f * gt[g]);
        }
    }

    crx_bits_pk<7, 6>(ex, cg[0], sg[0], AR, AI);
    crx_bits_pk<6, 5>(ex, cg[1], sg[1], AR, AI);
    crx_bits_pk<5, 4>(ex, cg[2], sg[2], AR, AI);
    crx_bits_pk<4, 3>(ex, cg[3], sg[3], AR, AI);
    crx_bits_pk<3, 2>(ex, cg[4], sg[4], AR, AI);
    crx_bits_pk<2, 1>(ex, cg[5], sg[5], AR, AI);
    crx_bits_pk<1, 0>(ex, cg[6], sg[6], AR, AI);
    crx_bits_pk<0, 7>(ex, cg[7], sg[7], AR, AI);
    crx_bits_pk<7, 6>(ex, cg[8], sg[8], AR, AI);
    crx_bits_pk<6, 5>(ex, cg[9], sg[9], AR, AI);

    // probabilities (packed), then reductions
    const float2 P0 = pk_fma(AR[0], AR[0], pk_mul(AI[0], AI[0]));
    const float2 P1 = pk_fma(AR[1], AR[1], pk_mul(AI[1], AI[1]));
    const float2 P2 = pk_fma(AR[2], AR[2], pk_mul(AI[2], AI[2]));
    const float2 P3 = pk_fma(AR[3], AR[3], pk_mul(AI[3], AI[3]));
    const float q00 = P0.x, q01 = P1.x, q02 = P2.x, q03 = P3.x;
    const float q10 = P0.y, q11 = P1.y, q12 = P2.y, q13 = P3.y;
    const float sgn3 = ((lane >> 2) & 1) ? -1.f : 1.f;
    float e3_0 = wave_sum(sgn3 * (q00 + q01 + q02 + q03), ex);
    float e7_0 = wave_sum((q00 - q01) + (q02 - q03), ex);
    float e3_1 = wave_sum(sgn3 * (q10 + q11 + q12 + q13), ex);
    float e7_1 = wave_sum((q10 - q11) + (q12 - q13), ex);

    // MLP head: lane 0 -> element 0, lane 1 -> element 1 (verified serial form)
    if (lane < 2) {
        const int   bo  = lane ? b1i  : b0;
        const float fe3 = lane ? e3_1 : e3_0;
        const float fe7 = lane ? e7_1 : e7_0;
        if (bo < Btot) {
            float acc = b2[0];
            #pragma unroll
            for (int j = 0; j < 10; ++j) {
                float h = tanhf(W1[2 * j] * fe3 + W1[2 * j + 1] * fe7 + b1[j]);
                acc += W2[j] * h;
            }
            out[bo] = 1.0f / (1.0f + expf(-acc));
        }
    }
}

extern "C" void kernel_launch(void* const* d_in, const int* in_sizes, int n_in,
                              void* d_out, int out_size, void* d_ws, size_t ws_size,
                              hipStream_t stream) {
    const float* x  = (const float*)d_in[0];
    const float* gt = (const float*)d_in[1];
    const float* W1 = (const float*)d_in[2];
    const float* b1 = (const float*)d_in[3];
    const float* W2 = (const float*)d_in[4];
    const float* b2 = (const float*)d_in[5];
    float* out = (float*)d_out;

    const int Btot  = in_sizes[0] / 2;          // x is (B, 2)
    const int waves = (Btot + 1) / 2;           // 2 elements per wave (packed)
    const int blocks = (waves + 3) / 4;         // 4 waves per 256-thread block

    float* cs = nullptr;
    if (ws_size >= 20 * sizeof(float)) {
        cs = (float*)d_ws;
        vqc_prep_kernel<<<1, 64, 0, stream>>>(gt, cs);
    }
    vqc_reg_kernel<<<blocks, 256, 0, stream>>>(x, gt, W1, b1, W2, b2, cs, out, Btot);
}